// Round 4
// baseline (341.921 us; speedup 1.0000x reference)
//
#include <hip/hip_runtime.h>

typedef __attribute__((ext_vector_type(8))) short bf16x8;
typedef __attribute__((ext_vector_type(4))) float f32x4;

// ---------- helpers ----------
__device__ __forceinline__ float bflo(unsigned u) { return __uint_as_float(u << 16); }
__device__ __forceinline__ float bfhi(unsigned u) { return __uint_as_float(u & 0xFFFF0000u); }
__device__ __forceinline__ unsigned f2bf(float f) {
  unsigned u = __float_as_uint(f);
  u = (u + 0x7FFFu + ((u >> 16) & 1u)) >> 16;
  return u;  // low 16 bits valid
}

// DPP-based add from lane (l ^ mask) within 16-lane row. VALU-speed (no LDS).
#define DPPADD(v, ctrl) \
  ((v) + __int_as_float(__builtin_amdgcn_update_dpp(0, __float_as_int(v), ctrl, 0xF, 0xF, true)))

// ---------- fp32 -> bf16 bulk convert (n multiple of 8) ----------
__global__ void cvt_bf16_kernel(const float* __restrict__ in, unsigned short* __restrict__ out,
                                int n8) {
  int i = blockIdx.x * 256 + threadIdx.x;
  if (i >= n8) return;
  const float4* p = (const float4*)(in + (size_t)i * 8);
  float4 x = p[0], y = p[1];
  uint4 v;
  v.x = f2bf(x.x) | (f2bf(x.y) << 16);
  v.y = f2bf(x.z) | (f2bf(x.w) << 16);
  v.z = f2bf(y.x) | (f2bf(y.y) << 16);
  v.w = f2bf(y.z) | (f2bf(y.w) << 16);
  *(uint4*)(out + (size_t)i * 8) = v;
}

// ---------- composed relation weights (bf16 out, fp32 bias) ----------
__global__ void compose_w_kernel(const float* __restrict__ Wk, const float* __restrict__ bk,
                                 const float* __restrict__ Wv, const float* __restrict__ bv,
                                 const float* __restrict__ rel_att, const float* __restrict__ rel_msg,
                                 const float* __restrict__ rel_pri,
                                 unsigned short* __restrict__ Wkr, float* __restrict__ bkr,
                                 unsigned short* __restrict__ Wvr, float* __restrict__ bvr) {
  int e = blockIdx.x;   // relation
  int o = blockIdx.y;   // out index 0..127
  int z = blockIdx.z;   // 0 = att(k), 1 = msg(v)
  int c = threadIdx.x;  // in index 0..127
  int hd = o >> 4, j = o & 15;
  const int se[3] = {0, 1, 0};
  int s = se[e];
  const float* W = z ? Wv : Wk;
  const float* b = z ? bv : bk;
  const float* R = z ? rel_msg : rel_att;
  float scale = z ? 1.0f : (rel_pri[e * 8 + hd] * 0.25f);  // 1/sqrt(16)=0.25
  float acc = 0.0f, bacc = 0.0f;
#pragma unroll
  for (int i = 0; i < 16; ++i) {
    float r = R[((e * 8 + hd) * 16 + i) * 16 + j];
    acc += W[(s * 128 + hd * 16 + i) * 128 + c] * r;
    bacc += b[s * 128 + hd * 16 + i] * r;
  }
  unsigned short* Wo = z ? Wvr : Wkr;
  float* bo = z ? bvr : bkr;
  Wo[((size_t)e * 128 + o) * 128 + c] = (unsigned short)f2bf(acc * scale);
  if (c == 0) bo[e * 128 + o] = bacc * scale;
}

// ---------- fused MFMA projection GEMM: A staged once, loop over weight mats ----------
struct ProjFP {
  const float* A[2];  // h0, h1 fp32
  int M[2];
  int nj[2];                     // 5, 3
  const unsigned short* W[10];   // [type*5 + j]
  const float* b[10];
  unsigned short* out[10];
  int ostr[10];                  // row stride in shorts
};

__global__ __launch_bounds__(256) void proj_gemm_fused(ProjFP P) {
  __shared__ short As[128 * 128];
  __shared__ short Bs[128 * 128];
  int type = blockIdx.y;
  const float* __restrict__ A = P.A[type];
  int M = P.M[type];
  int nj = P.nj[type];
  int base = type * 5;
  int row0 = blockIdx.x * 128;
  if (row0 >= M) return;
  int t = threadIdx.x;
  bool full = (row0 + 128 <= M);
  // stage A (fp32 -> bf16) once
#pragma unroll
  for (int it = 0; it < 8; ++it) {
    int o = (it * 256 + t) * 8;
    int row = o >> 7, col = o & 127;
    int gr = row0 + row;
    uint4 av = make_uint4(0, 0, 0, 0);
    if (full || gr < M) {
      float4 x = *(const float4*)(A + (size_t)gr * 128 + col);
      float4 y = *(const float4*)(A + (size_t)gr * 128 + col + 4);
      av.x = f2bf(x.x) | (f2bf(x.y) << 16);
      av.y = f2bf(x.z) | (f2bf(x.w) << 16);
      av.z = f2bf(y.x) | (f2bf(y.y) << 16);
      av.w = f2bf(y.z) | (f2bf(y.w) << 16);
    }
    int sw = o ^ ((row & 7) << 3);
    *(uint4*)(&As[sw]) = av;
  }
  // stage B for job 0
  {
    const unsigned short* W0 = P.W[base];
#pragma unroll
    for (int it = 0; it < 8; ++it) {
      int o = (it * 256 + t) * 8;
      int row = o >> 7;
      int sw = o ^ ((row & 7) << 3);
      *(uint4*)(&Bs[sw]) = *(const uint4*)(W0 + o);
    }
  }
  __syncthreads();
  int wid = t >> 6, l = t & 63;
  int wr = wid >> 1, wc = wid & 1;  // 2x2 waves, 64x64 each
  int lr = l & 15, kb = l >> 4;
  for (int j = 0;; ++j) {
    f32x4 acc[4][4] = {};
#pragma unroll
    for (int ks = 0; ks < 4; ++ks) {
      bf16x8 af[4], bfr[4];
#pragma unroll
      for (int m = 0; m < 4; ++m) {
        int row = wr * 64 + m * 16 + lr;
        int h = (row * 128 + kb * 8 + ks * 32) ^ ((row & 7) << 3);
        af[m] = *(bf16x8*)(&As[h]);
      }
#pragma unroll
      for (int n = 0; n < 4; ++n) {
        int row = wc * 64 + n * 16 + lr;
        int h = (row * 128 + kb * 8 + ks * 32) ^ ((row & 7) << 3);
        bfr[n] = *(bf16x8*)(&Bs[h]);
      }
#pragma unroll
      for (int m = 0; m < 4; ++m)
#pragma unroll
        for (int n = 0; n < 4; ++n)
          acc[m][n] = __builtin_amdgcn_mfma_f32_16x16x32_bf16(af[m], bfr[n], acc[m][n], 0, 0, 0);
    }
    // epilogue for job j
    const float* bias = P.b[base + j];
    unsigned short* out = P.out[base + j];
    int ostr = P.ostr[base + j];
    int rb = row0 + wr * 64 + (l >> 4) * 4;
#pragma unroll
    for (int m = 0; m < 4; ++m)
#pragma unroll
      for (int jr = 0; jr < 4; ++jr) {
        int grow = rb + m * 16 + jr;
        if (grow < M) {
#pragma unroll
          for (int n = 0; n < 4; ++n) {
            int col = wc * 64 + n * 16 + lr;
            out[(size_t)grow * ostr + col] = (unsigned short)f2bf(acc[m][n][jr] + bias[col]);
          }
        }
      }
    if (j + 1 >= nj) break;
    __syncthreads();
    {
      const unsigned short* Wj = P.W[base + j + 1];
#pragma unroll
      for (int it = 0; it < 8; ++it) {
        int o = (it * 256 + t) * 8;
        int row = o >> 7;
        int sw = o ^ ((row & 7) << 3);
        *(uint4*)(&Bs[sw]) = *(const uint4*)(Wj + o);
      }
    }
    __syncthreads();
  }
}

// ---------- MFMA final GEMM: d_out = a*(Tb@Wa^T+ba) + (1-a)*h ----------
__global__ __launch_bounds__(256) void final_gemm_mfma(
    float* __restrict__ dout, const unsigned short* __restrict__ Tb0,
    const unsigned short* __restrict__ Tb1, const unsigned short* __restrict__ Wab,
    const float* __restrict__ ba, const float* __restrict__ h0, const float* __restrict__ h1,
    const float* __restrict__ skip, int N0, int N1) {
  __shared__ short As[128 * 128];
  __shared__ short Bs[128 * 128];
  int type = blockIdx.y;
  int M = type ? N1 : N0;
  const unsigned short* T = type ? Tb1 : Tb0;
  const unsigned short* W = Wab + (size_t)type * 16384;
  const float* bias = ba + type * 128;
  const float* h = type ? h1 : h0;
  float* O = dout + (type ? (size_t)N0 * 128 : 0);
  int row0 = blockIdx.x * 128;
  if (row0 >= M) return;
  int t = threadIdx.x;
  bool full = (row0 + 128 <= M);
#pragma unroll
  for (int it = 0; it < 8; ++it) {
    int o = (it * 256 + t) * 8;
    int row = o >> 7;
    int gr = row0 + row;
    uint4 av = make_uint4(0, 0, 0, 0);
    if (full || gr < M) av = *(const uint4*)(T + (size_t)gr * 128 + (o & 127));
    int sw = o ^ ((row & 7) << 3);
    *(uint4*)(&As[sw]) = av;
    uint4 wv = *(const uint4*)(W + o);
    *(uint4*)(&Bs[sw]) = wv;
  }
  __syncthreads();
  int wid = t >> 6, l = t & 63;
  int wr = wid >> 1, wc = wid & 1;
  int lr = l & 15, kb = l >> 4;
  f32x4 acc[4][4] = {};
#pragma unroll
  for (int ks = 0; ks < 4; ++ks) {
    bf16x8 af[4], bfr[4];
#pragma unroll
    for (int m = 0; m < 4; ++m) {
      int row = wr * 64 + m * 16 + lr;
      int h2 = (row * 128 + kb * 8 + ks * 32) ^ ((row & 7) << 3);
      af[m] = *(bf16x8*)(&As[h2]);
    }
#pragma unroll
    for (int n = 0; n < 4; ++n) {
      int row = wc * 64 + n * 16 + lr;
      int h2 = (row * 128 + kb * 8 + ks * 32) ^ ((row & 7) << 3);
      bfr[n] = *(bf16x8*)(&Bs[h2]);
    }
#pragma unroll
    for (int m = 0; m < 4; ++m)
#pragma unroll
      for (int n = 0; n < 4; ++n)
        acc[m][n] = __builtin_amdgcn_mfma_f32_16x16x32_bf16(af[m], bfr[n], acc[m][n], 0, 0, 0);
  }
  float alpha = 1.0f / (1.0f + __expf(-skip[type]));
  float beta = 1.0f - alpha;
  int rb = row0 + wr * 64 + (l >> 4) * 4;
#pragma unroll
  for (int m = 0; m < 4; ++m)
#pragma unroll
    for (int jr = 0; jr < 4; ++jr) {
      int grow = rb + m * 16 + jr;
      if (grow < M) {
#pragma unroll
        for (int n = 0; n < 4; ++n) {
          int col = wc * 64 + n * 16 + lr;
          float vout = alpha * (acc[m][n][jr] + bias[col]) + beta * h[(size_t)grow * 128 + col];
          O[(size_t)grow * 128 + col] = vout;
        }
      }
    }
}

// ---------- CSR build (batched over 3 relations via gridDim.y) ----------
__global__ void hist3_kernel(const int* __restrict__ d0, const int* __restrict__ d1,
                             const int* __restrict__ d2, int* __restrict__ cnt, int maxN, int E) {
  int r = blockIdx.y;
  int i = blockIdx.x * 256 + threadIdx.x;
  const int* dst = r == 0 ? d0 : (r == 1 ? d1 : d2);
  if (i < E) atomicAdd(&cnt[(size_t)r * maxN + dst[i]], 1);
}

__global__ void scan1_kernel(const int* __restrict__ cnt, int* __restrict__ rp0,
                             int* __restrict__ rp1, int* __restrict__ rp2,
                             int* __restrict__ bsum, int maxN, int n0, int n1, int n2) {
  __shared__ int sd[256];
  int r = blockIdx.y;
  int n = r == 0 ? n0 : (r == 1 ? n1 : n2);
  int* rp = r == 0 ? rp0 : (r == 1 ? rp1 : rp2);
  const int* c = cnt + (size_t)r * maxN;
  int t = threadIdx.x;
  int base = blockIdx.x * 1024 + t * 4;
  int x[4];
#pragma unroll
  for (int j = 0; j < 4; ++j) x[j] = (base + j < n) ? c[base + j] : 0;
  int tsum = x[0] + x[1] + x[2] + x[3];
  sd[t] = tsum;
  __syncthreads();
  for (int off = 1; off < 256; off <<= 1) {
    int v = (t >= off) ? sd[t - off] : 0;
    __syncthreads();
    sd[t] += v;
    __syncthreads();
  }
  int run = sd[t] - tsum;  // exclusive
#pragma unroll
  for (int j = 0; j < 4; ++j) {
    if (base + j < n) rp[base + j] = run;
    run += x[j];
  }
  if (t == 255) bsum[r * 256 + blockIdx.x] = sd[255];
}

__global__ void scan2_kernel(int* __restrict__ bsum, int nb) {
  __shared__ int sd[256];
  int r = blockIdx.y;
  int* bs = bsum + r * 256;
  int t = threadIdx.x;
  int v = (t < nb) ? bs[t] : 0;
  sd[t] = v;
  __syncthreads();
  for (int off = 1; off < 256; off <<= 1) {
    int u = (t >= off) ? sd[t - off] : 0;
    __syncthreads();
    sd[t] += u;
    __syncthreads();
  }
  if (t < nb) bs[t] = sd[t] - v;  // exclusive
}

__global__ void scan3_kernel(int* __restrict__ rp0, int* __restrict__ rp1, int* __restrict__ rp2,
                             const int* __restrict__ bsum, int n0, int n1, int n2, int total) {
  int r = blockIdx.y;
  int n = r == 0 ? n0 : (r == 1 ? n1 : n2);
  int* rp = r == 0 ? rp0 : (r == 1 ? rp1 : rp2);
  int i = blockIdx.x * 256 + threadIdx.x;
  if (i < n) rp[i] += bsum[r * 256 + (i >> 10)];
  if (blockIdx.x == 0 && threadIdx.x == 0) rp[n] = total;
}

__global__ void scatter3_kernel(const int* __restrict__ s0, const int* __restrict__ d0,
                                const int* __restrict__ s1, const int* __restrict__ d1,
                                const int* __restrict__ s2, const int* __restrict__ d2,
                                const int* __restrict__ rp0, const int* __restrict__ rp1,
                                const int* __restrict__ rp2, int* __restrict__ cur, int maxN,
                                int* __restrict__ ss0, int* __restrict__ ss1,
                                int* __restrict__ ss2, int E) {
  int r = blockIdx.y;
  int i = blockIdx.x * 256 + threadIdx.x;
  if (i >= E) return;
  const int* src = r == 0 ? s0 : (r == 1 ? s1 : s2);
  const int* dst = r == 0 ? d0 : (r == 1 ? d1 : d2);
  const int* rp = r == 0 ? rp0 : (r == 1 ? rp1 : rp2);
  int* ss = r == 0 ? ss0 : (r == 1 ? ss1 : ss2);
  int d = dst[i];
  int pos = rp[d] + atomicAdd(&cur[(size_t)r * maxN + d], 1);
  ss[pos] = src[i];
}

// ---------- edge aggregation: one wave per dst node, 8-edge pipelined batches ----------
struct AggP {
  const unsigned *qb0, *qb1, *kv0, *kv1, *kv2;
  const int *rp0, *ss0, *rp1, *ss1, *rp2, *ss2;
  unsigned *Tb0, *Tb1;
  int N0, N1;
};

// load ss[p..p+7] (clamped) and the 16 kv rows for those 8 edges
__device__ __forceinline__ void load8(const unsigned* __restrict__ kv,
                                      const int* __restrict__ ss, int p, int end, int l,
                                      unsigned kb[8], unsigned vb[8]) {
  int lastp = end - 1;
  int idx = p + (l & 7);
  idx = idx > lastp ? lastp : idx;
  int sv = ss[idx];  // lanes 0..7 hold the 8 edge srcs (repeated in upper groups)
  int s[8];
#pragma unroll
  for (int g = 0; g < 8; ++g) s[g] = __builtin_amdgcn_readlane(sv, g);
#pragma unroll
  for (int g = 0; g < 8; ++g) {
    const unsigned* r = kv + (size_t)s[g] * 128;
    kb[g] = r[l];
    vb[g] = r[64 + l];
  }
}

__device__ __forceinline__ void compute8(int p, int end, const unsigned kb[8],
                                         const unsigned vb[8], float qx, float qy,
                                         float& ax, float& ay, float& den) {
#pragma unroll
  for (int g = 0; g < 8; ++g) {
    float sc = qx * bflo(kb[g]) + qy * bfhi(kb[g]);
    // 8-lane head reduce: xor1, xor2 (quad_perm), xor7 (row_half_mirror)
    sc = DPPADD(sc, 0xB1);
    sc = DPPADD(sc, 0x4E);
    sc = DPPADD(sc, 0x141);
    float e = __expf(sc);
    if (g) e *= (p + g < end) ? 1.f : 0.f;  // g=0 always valid
    den += e;
    ax += e * bflo(vb[g]);
    ay += e * bfhi(vb[g]);
  }
}

__device__ __forceinline__ void accum_rel(const unsigned* __restrict__ kv,
                                          const int* __restrict__ rp, const int* __restrict__ ss,
                                          int node, int l, float qx, float qy,
                                          float& rx, float& ry) {
  int beg = __builtin_amdgcn_readfirstlane(rp[node]);
  int end = __builtin_amdgcn_readfirstlane(rp[node + 1]);
  if (end <= beg) return;
  float ax = 0.f, ay = 0.f, den = 0.f;
  unsigned ka[8], va[8], kb[8], vb[8];
  int p = beg;
  load8(kv, ss, p, end, l, ka, va);
  for (;;) {
    if (p + 8 < end) load8(kv, ss, p + 8, end, l, kb, vb);
    compute8(p, end, ka, va, qx, qy, ax, ay, den);
    p += 8;
    if (p >= end) break;
    if (p + 8 < end) load8(kv, ss, p + 8, end, l, ka, va);
    compute8(p, end, kb, vb, qx, qy, ax, ay, den);
    p += 8;
    if (p >= end) break;
  }
  float inv = 1.0f / den;
  rx += ax * inv;
  ry += ay * inv;
}

__global__ __launch_bounds__(256) void agg_all_kernel(AggP P) {
  int gw = (blockIdx.x * 256 + threadIdx.x) >> 6;
  int l = threadIdx.x & 63;
  if (gw < P.N0) {
    unsigned q = P.qb0[(size_t)gw * 64 + l];
    float qx = bflo(q), qy = bfhi(q);
    float rx = 0.f, ry = 0.f;
    accum_rel(P.kv1, P.rp1, P.ss1, gw, l, qx, qy, rx, ry);
    accum_rel(P.kv2, P.rp2, P.ss2, gw, l, qx, qy, rx, ry);
    P.Tb0[(size_t)gw * 64 + l] = f2bf(rx * 0.5f) | (f2bf(ry * 0.5f) << 16);
  } else if (gw < P.N0 + P.N1) {
    int n = gw - P.N0;
    unsigned q = P.qb1[(size_t)n * 64 + l];
    float qx = bflo(q), qy = bfhi(q);
    float rx = 0.f, ry = 0.f;
    accum_rel(P.kv0, P.rp0, P.ss0, n, l, qx, qy, rx, ry);
    P.Tb1[(size_t)n * 64 + l] = f2bf(rx) | (f2bf(ry) << 16);
  }
}

// ---------- host ----------
extern "C" void kernel_launch(void* const* d_in, const int* in_sizes, int n_in,
                              void* d_out, int out_size, void* d_ws, size_t ws_size,
                              hipStream_t stream) {
  const float* h0 = (const float*)d_in[0];
  const float* h1 = (const float*)d_in[1];
  const int* srcs[3] = {(const int*)d_in[2], (const int*)d_in[4], (const int*)d_in[6]};
  const int* dsts[3] = {(const int*)d_in[3], (const int*)d_in[5], (const int*)d_in[7]};
  const float* Wk = (const float*)d_in[8];
  const float* bk = (const float*)d_in[9];
  const float* Wq = (const float*)d_in[10];
  const float* bq = (const float*)d_in[11];
  const float* Wv = (const float*)d_in[12];
  const float* bv = (const float*)d_in[13];
  const float* Wa = (const float*)d_in[14];
  const float* ba = (const float*)d_in[15];
  const float* rel_att = (const float*)d_in[16];
  const float* rel_msg = (const float*)d_in[17];
  const float* rel_pri = (const float*)d_in[18];
  const float* skip = (const float*)d_in[19];

  int N0 = in_sizes[0] / 128;
  int N1 = in_sizes[1] / 128;
  int E = in_sizes[2];
  int nsrc[3] = {N0, N1, N0};
  int ndst[3] = {N1, N0, N0};
  int maxN = N0 > N1 ? N0 : N1;

  char* base = (char*)d_ws;
  size_t off = 0;
  auto alloc = [&](size_t bytes) -> void* {
    void* p = base + off;
    off += (bytes + 255) & ~(size_t)255;
    return p;
  };

  unsigned short* qb0 = (unsigned short*)alloc((size_t)N0 * 128 * 2);
  unsigned short* qb1 = (unsigned short*)alloc((size_t)N1 * 128 * 2);
  unsigned short* kvb[3];  // interleaved [N][kr(128) | vr(128)] bf16
  for (int r = 0; r < 3; ++r) kvb[r] = (unsigned short*)alloc((size_t)nsrc[r] * 256 * 2);
  unsigned short* Tb0 = (unsigned short*)alloc((size_t)N0 * 128 * 2);
  unsigned short* Tb1 = (unsigned short*)alloc((size_t)N1 * 128 * 2);
  unsigned short* Wkrb = (unsigned short*)alloc((size_t)3 * 16384 * 2);
  unsigned short* Wvrb = (unsigned short*)alloc((size_t)3 * 16384 * 2);
  unsigned short* Wqb = (unsigned short*)alloc((size_t)2 * 16384 * 2);
  unsigned short* Wab = (unsigned short*)alloc((size_t)2 * 16384 * 2);
  float* bkr = (float*)alloc(3 * 128 * 4);
  float* bvr = (float*)alloc(3 * 128 * 4);
  int* rp[3];
  int* ss[3];
  for (int r = 0; r < 3; ++r) {
    rp[r] = (int*)alloc((size_t)(ndst[r] + 1) * 4);
    ss[r] = (int*)alloc((size_t)(E + 8) * 4);
  }
  int* cnt6 = (int*)alloc((size_t)6 * maxN * 4);  // cnt (hist) + cur (scatter)
  int* bsum = (int*)alloc(3 * 256 * 4);
  (void)ws_size;

  // 1. weight prep
  compose_w_kernel<<<dim3(3, 128, 2), 128, 0, stream>>>(Wk, bk, Wv, bv, rel_att, rel_msg,
                                                        rel_pri, Wkrb, bkr, Wvrb, bvr);
  cvt_bf16_kernel<<<16, 256, 0, stream>>>(Wq, Wqb, 4096);
  cvt_bf16_kernel<<<16, 256, 0, stream>>>(Wa, Wab, 4096);

  // 2. fused projection GEMMs -> bf16 q + interleaved kv tables
  ProjFP pf;
  pf.A[0] = h0; pf.A[1] = h1;
  pf.M[0] = N0; pf.M[1] = N1;
  pf.nj[0] = 5; pf.nj[1] = 3;
  // type0 jobs: q, kr(rel0), kr(rel2), vr(rel0), vr(rel2)
  pf.W[0] = Wqb;            pf.b[0] = bq;        pf.out[0] = qb0;          pf.ostr[0] = 128;
  pf.W[1] = Wkrb;           pf.b[1] = bkr;       pf.out[1] = kvb[0];       pf.ostr[1] = 256;
  pf.W[2] = Wkrb + 32768;   pf.b[2] = bkr + 256; pf.out[2] = kvb[2];       pf.ostr[2] = 256;
  pf.W[3] = Wvrb;           pf.b[3] = bvr;       pf.out[3] = kvb[0] + 128; pf.ostr[3] = 256;
  pf.W[4] = Wvrb + 32768;   pf.b[4] = bvr + 256; pf.out[4] = kvb[2] + 128; pf.ostr[4] = 256;
  // type1 jobs: q, kr(rel1), vr(rel1)
  pf.W[5] = Wqb + 16384;    pf.b[5] = bq + 128;  pf.out[5] = qb1;          pf.ostr[5] = 128;
  pf.W[6] = Wkrb + 16384;   pf.b[6] = bkr + 128; pf.out[6] = kvb[1];       pf.ostr[6] = 256;
  pf.W[7] = Wvrb + 16384;   pf.b[7] = bvr + 128; pf.out[7] = kvb[1] + 128; pf.ostr[7] = 256;
  pf.W[8] = Wqb; pf.b[8] = bq; pf.out[8] = qb0; pf.ostr[8] = 128;  // unused
  pf.W[9] = Wqb; pf.b[9] = bq; pf.out[9] = qb0; pf.ostr[9] = 128;  // unused
  proj_gemm_fused<<<dim3((maxN + 127) / 128, 2), 256, 0, stream>>>(pf);

  // 3. CSR per relation (batched, gridDim.y = 3)
  hipMemsetAsync(cnt6, 0, (size_t)6 * maxN * 4, stream);
  hist3_kernel<<<dim3((E + 255) / 256, 3), 256, 0, stream>>>(dsts[0], dsts[1], dsts[2], cnt6,
                                                             maxN, E);
  int nb = (maxN + 1023) / 1024;
  scan1_kernel<<<dim3(nb, 3), 256, 0, stream>>>(cnt6, rp[0], rp[1], rp[2], bsum, maxN,
                                                ndst[0], ndst[1], ndst[2]);
  scan2_kernel<<<dim3(1, 3), 256, 0, stream>>>(bsum, nb);
  scan3_kernel<<<dim3((maxN + 255) / 256, 3), 256, 0, stream>>>(rp[0], rp[1], rp[2], bsum,
                                                                ndst[0], ndst[1], ndst[2], E);
  scatter3_kernel<<<dim3((E + 255) / 256, 3), 256, 0, stream>>>(
      srcs[0], dsts[0], srcs[1], dsts[1], srcs[2], dsts[2], rp[0], rp[1], rp[2],
      cnt6 + (size_t)3 * maxN, maxN, ss[0], ss[1], ss[2], E);

  // 4. edge aggregation -> bf16 T (one kernel, both types)
  AggP ap;
  ap.qb0 = (const unsigned*)qb0; ap.qb1 = (const unsigned*)qb1;
  ap.kv0 = (const unsigned*)kvb[0]; ap.kv1 = (const unsigned*)kvb[1];
  ap.kv2 = (const unsigned*)kvb[2];
  ap.rp0 = rp[0]; ap.ss0 = ss[0];
  ap.rp1 = rp[1]; ap.ss1 = ss[1];
  ap.rp2 = rp[2]; ap.ss2 = ss[2];
  ap.Tb0 = (unsigned*)Tb0; ap.Tb1 = (unsigned*)Tb1;
  ap.N0 = N0; ap.N1 = N1;
  int totw = N0 + N1;
  agg_all_kernel<<<(totw + 3) / 4, 256, 0, stream>>>(ap);

  // 5. final GEMM + skip blend -> fp32 d_out
  final_gemm_mfma<<<dim3((maxN + 127) / 128, 2), 256, 0, stream>>>(
      (float*)d_out, Tb0, Tb1, Wab, ba, h0, h1, skip, N0, N1);
}

// Round 5
// 330.060 us; speedup vs baseline: 1.0359x; 1.0359x over previous
//
#include <hip/hip_runtime.h>

typedef __attribute__((ext_vector_type(8))) short bf16x8;
typedef __attribute__((ext_vector_type(4))) float f32x4;

// ---------- helpers ----------
__device__ __forceinline__ float bflo(unsigned u) { return __uint_as_float(u << 16); }
__device__ __forceinline__ float bfhi(unsigned u) { return __uint_as_float(u & 0xFFFF0000u); }
__device__ __forceinline__ unsigned f2bf(float f) {
  unsigned u = __float_as_uint(f);
  u = (u + 0x7FFFu + ((u >> 16) & 1u)) >> 16;
  return u;  // low 16 bits valid
}

// DPP-based add from lane (l ^ mask) within quad. VALU-speed (no LDS).
#define DPPADD(v, ctrl) \
  ((v) + __int_as_float(__builtin_amdgcn_update_dpp(0, __float_as_int(v), ctrl, 0xF, 0xF, true)))

// ---------- fp32 -> bf16 bulk convert, two arrays in one launch ----------
__global__ void cvt2_kernel(const float* __restrict__ a, unsigned short* __restrict__ oa,
                            const float* __restrict__ b, unsigned short* __restrict__ ob,
                            int n8) {
  int i = blockIdx.x * 256 + threadIdx.x;
  if (i >= n8) return;
  const float* in = blockIdx.y ? b : a;
  unsigned short* out = blockIdx.y ? ob : oa;
  const float4* p = (const float4*)(in + (size_t)i * 8);
  float4 x = p[0], y = p[1];
  uint4 v;
  v.x = f2bf(x.x) | (f2bf(x.y) << 16);
  v.y = f2bf(x.z) | (f2bf(x.w) << 16);
  v.z = f2bf(y.x) | (f2bf(y.y) << 16);
  v.w = f2bf(y.z) | (f2bf(y.w) << 16);
  *(uint4*)(out + (size_t)i * 8) = v;
}

// ---------- composed relation weights (bf16 out, fp32 bias) ----------
__global__ void compose_w_kernel(const float* __restrict__ Wk, const float* __restrict__ bk,
                                 const float* __restrict__ Wv, const float* __restrict__ bv,
                                 const float* __restrict__ rel_att, const float* __restrict__ rel_msg,
                                 const float* __restrict__ rel_pri,
                                 unsigned short* __restrict__ Wkr, float* __restrict__ bkr,
                                 unsigned short* __restrict__ Wvr, float* __restrict__ bvr) {
  int e = blockIdx.x;   // relation
  int o = blockIdx.y;   // out index 0..127
  int z = blockIdx.z;   // 0 = att(k), 1 = msg(v)
  int c = threadIdx.x;  // in index 0..127
  int hd = o >> 4, j = o & 15;
  const int se[3] = {0, 1, 0};
  int s = se[e];
  const float* W = z ? Wv : Wk;
  const float* b = z ? bv : bk;
  const float* R = z ? rel_msg : rel_att;
  float scale = z ? 1.0f : (rel_pri[e * 8 + hd] * 0.25f);  // 1/sqrt(16)=0.25
  float acc = 0.0f, bacc = 0.0f;
#pragma unroll
  for (int i = 0; i < 16; ++i) {
    float r = R[((e * 8 + hd) * 16 + i) * 16 + j];
    acc += W[(s * 128 + hd * 16 + i) * 128 + c] * r;
    bacc += b[s * 128 + hd * 16 + i] * r;
  }
  unsigned short* Wo = z ? Wvr : Wkr;
  float* bo = z ? bvr : bkr;
  Wo[((size_t)e * 128 + o) * 128 + c] = (unsigned short)f2bf(acc * scale);
  if (c == 0) bo[e * 128 + o] = bacc * scale;
}

// ---------- fused MFMA projection GEMM: A staged once, loop over weight mats ----------
struct ProjFP {
  const float* A[2];  // h0, h1 fp32
  int M[2];
  int nj[2];                     // 5, 3
  const unsigned short* W[10];   // [type*5 + j]
  const float* b[10];
  unsigned short* out[10];
  int ostr[10];                  // row stride in shorts
};

__global__ __launch_bounds__(256) void proj_gemm_fused(ProjFP P) {
  __shared__ short As[128 * 128];
  __shared__ short Bs[128 * 128];
  int type = blockIdx.y;
  const float* __restrict__ A = P.A[type];
  int M = P.M[type];
  int nj = P.nj[type];
  int base = type * 5;
  int row0 = blockIdx.x * 128;
  if (row0 >= M) return;
  int t = threadIdx.x;
  bool full = (row0 + 128 <= M);
  // stage A (fp32 -> bf16) once
#pragma unroll
  for (int it = 0; it < 8; ++it) {
    int o = (it * 256 + t) * 8;
    int row = o >> 7, col = o & 127;
    int gr = row0 + row;
    uint4 av = make_uint4(0, 0, 0, 0);
    if (full || gr < M) {
      float4 x = *(const float4*)(A + (size_t)gr * 128 + col);
      float4 y = *(const float4*)(A + (size_t)gr * 128 + col + 4);
      av.x = f2bf(x.x) | (f2bf(x.y) << 16);
      av.y = f2bf(x.z) | (f2bf(x.w) << 16);
      av.z = f2bf(y.x) | (f2bf(y.y) << 16);
      av.w = f2bf(y.z) | (f2bf(y.w) << 16);
    }
    int sw = o ^ ((row & 7) << 3);
    *(uint4*)(&As[sw]) = av;
  }
  // stage B for job 0
  {
    const unsigned short* W0 = P.W[base];
#pragma unroll
    for (int it = 0; it < 8; ++it) {
      int o = (it * 256 + t) * 8;
      int row = o >> 7;
      int sw = o ^ ((row & 7) << 3);
      *(uint4*)(&Bs[sw]) = *(const uint4*)(W0 + o);
    }
  }
  __syncthreads();
  int wid = t >> 6, l = t & 63;
  int wr = wid >> 1, wc = wid & 1;  // 2x2 waves, 64x64 each
  int lr = l & 15, kb = l >> 4;
  for (int j = 0;; ++j) {
    f32x4 acc[4][4] = {};
#pragma unroll
    for (int ks = 0; ks < 4; ++ks) {
      bf16x8 af[4], bfr[4];
#pragma unroll
      for (int m = 0; m < 4; ++m) {
        int row = wr * 64 + m * 16 + lr;
        int h = (row * 128 + kb * 8 + ks * 32) ^ ((row & 7) << 3);
        af[m] = *(bf16x8*)(&As[h]);
      }
#pragma unroll
      for (int n = 0; n < 4; ++n) {
        int row = wc * 64 + n * 16 + lr;
        int h = (row * 128 + kb * 8 + ks * 32) ^ ((row & 7) << 3);
        bfr[n] = *(bf16x8*)(&Bs[h]);
      }
#pragma unroll
      for (int m = 0; m < 4; ++m)
#pragma unroll
        for (int n = 0; n < 4; ++n)
          acc[m][n] = __builtin_amdgcn_mfma_f32_16x16x32_bf16(af[m], bfr[n], acc[m][n], 0, 0, 0);
    }
    // epilogue for job j
    const float* bias = P.b[base + j];
    unsigned short* out = P.out[base + j];
    int ostr = P.ostr[base + j];
    int rb = row0 + wr * 64 + (l >> 4) * 4;
#pragma unroll
    for (int m = 0; m < 4; ++m)
#pragma unroll
      for (int jr = 0; jr < 4; ++jr) {
        int grow = rb + m * 16 + jr;
        if (grow < M) {
#pragma unroll
          for (int n = 0; n < 4; ++n) {
            int col = wc * 64 + n * 16 + lr;
            out[(size_t)grow * ostr + col] = (unsigned short)f2bf(acc[m][n][jr] + bias[col]);
          }
        }
      }
    if (j + 1 >= nj) break;
    __syncthreads();
    {
      const unsigned short* Wj = P.W[base + j + 1];
#pragma unroll
      for (int it = 0; it < 8; ++it) {
        int o = (it * 256 + t) * 8;
        int row = o >> 7;
        int sw = o ^ ((row & 7) << 3);
        *(uint4*)(&Bs[sw]) = *(const uint4*)(Wj + o);
      }
    }
    __syncthreads();
  }
}

// ---------- MFMA final GEMM: d_out = a*(Tb@Wa^T+ba) + (1-a)*h ----------
__global__ __launch_bounds__(256) void final_gemm_mfma(
    float* __restrict__ dout, const unsigned short* __restrict__ Tb0,
    const unsigned short* __restrict__ Tb1, const unsigned short* __restrict__ Wab,
    const float* __restrict__ ba, const float* __restrict__ h0, const float* __restrict__ h1,
    const float* __restrict__ skip, int N0, int N1) {
  __shared__ short As[128 * 128];
  __shared__ short Bs[128 * 128];
  int type = blockIdx.y;
  int M = type ? N1 : N0;
  const unsigned short* T = type ? Tb1 : Tb0;
  const unsigned short* W = Wab + (size_t)type * 16384;
  const float* bias = ba + type * 128;
  const float* h = type ? h1 : h0;
  float* O = dout + (type ? (size_t)N0 * 128 : 0);
  int row0 = blockIdx.x * 128;
  if (row0 >= M) return;
  int t = threadIdx.x;
  bool full = (row0 + 128 <= M);
#pragma unroll
  for (int it = 0; it < 8; ++it) {
    int o = (it * 256 + t) * 8;
    int row = o >> 7;
    int gr = row0 + row;
    uint4 av = make_uint4(0, 0, 0, 0);
    if (full || gr < M) av = *(const uint4*)(T + (size_t)gr * 128 + (o & 127));
    int sw = o ^ ((row & 7) << 3);
    *(uint4*)(&As[sw]) = av;
    uint4 wv = *(const uint4*)(W + o);
    *(uint4*)(&Bs[sw]) = wv;
  }
  __syncthreads();
  int wid = t >> 6, l = t & 63;
  int wr = wid >> 1, wc = wid & 1;
  int lr = l & 15, kb = l >> 4;
  f32x4 acc[4][4] = {};
#pragma unroll
  for (int ks = 0; ks < 4; ++ks) {
    bf16x8 af[4], bfr[4];
#pragma unroll
    for (int m = 0; m < 4; ++m) {
      int row = wr * 64 + m * 16 + lr;
      int h2 = (row * 128 + kb * 8 + ks * 32) ^ ((row & 7) << 3);
      af[m] = *(bf16x8*)(&As[h2]);
    }
#pragma unroll
    for (int n = 0; n < 4; ++n) {
      int row = wc * 64 + n * 16 + lr;
      int h2 = (row * 128 + kb * 8 + ks * 32) ^ ((row & 7) << 3);
      bfr[n] = *(bf16x8*)(&Bs[h2]);
    }
#pragma unroll
    for (int m = 0; m < 4; ++m)
#pragma unroll
      for (int n = 0; n < 4; ++n)
        acc[m][n] = __builtin_amdgcn_mfma_f32_16x16x32_bf16(af[m], bfr[n], acc[m][n], 0, 0, 0);
  }
  float alpha = 1.0f / (1.0f + __expf(-skip[type]));
  float beta = 1.0f - alpha;
  int rb = row0 + wr * 64 + (l >> 4) * 4;
#pragma unroll
  for (int m = 0; m < 4; ++m)
#pragma unroll
    for (int jr = 0; jr < 4; ++jr) {
      int grow = rb + m * 16 + jr;
      if (grow < M) {
#pragma unroll
        for (int n = 0; n < 4; ++n) {
          int col = wc * 64 + n * 16 + lr;
          float vout = alpha * (acc[m][n][jr] + bias[col]) + beta * h[(size_t)grow * 128 + col];
          O[(size_t)grow * 128 + col] = vout;
        }
      }
    }
}

// ---------- CSR build (batched over 3 relations via gridDim.y) ----------
__global__ void hist3_kernel(const int* __restrict__ d0, const int* __restrict__ d1,
                             const int* __restrict__ d2, int* __restrict__ cnt, int maxN, int E) {
  int r = blockIdx.y;
  int i = blockIdx.x * 256 + threadIdx.x;
  const int* dst = r == 0 ? d0 : (r == 1 ? d1 : d2);
  if (i < E) atomicAdd(&cnt[(size_t)r * maxN + dst[i]], 1);
}

__global__ void scan1_kernel(const int* __restrict__ cnt, int* __restrict__ rp0,
                             int* __restrict__ rp1, int* __restrict__ rp2,
                             int* __restrict__ bsum, int maxN, int n0, int n1, int n2) {
  __shared__ int sd[256];
  int r = blockIdx.y;
  int n = r == 0 ? n0 : (r == 1 ? n1 : n2);
  int* rp = r == 0 ? rp0 : (r == 1 ? rp1 : rp2);
  const int* c = cnt + (size_t)r * maxN;
  int t = threadIdx.x;
  int base = blockIdx.x * 1024 + t * 4;
  int x[4];
#pragma unroll
  for (int j = 0; j < 4; ++j) x[j] = (base + j < n) ? c[base + j] : 0;
  int tsum = x[0] + x[1] + x[2] + x[3];
  sd[t] = tsum;
  __syncthreads();
  for (int off = 1; off < 256; off <<= 1) {
    int v = (t >= off) ? sd[t - off] : 0;
    __syncthreads();
    sd[t] += v;
    __syncthreads();
  }
  int run = sd[t] - tsum;  // exclusive
#pragma unroll
  for (int j = 0; j < 4; ++j) {
    if (base + j < n) rp[base + j] = run;
    run += x[j];
  }
  if (t == 255) bsum[r * 256 + blockIdx.x] = sd[255];
}

// fused scan2+scan3: each block redundantly scans the <=256-entry block sums in LDS
__global__ void scan23_kernel(int* __restrict__ rp0, int* __restrict__ rp1, int* __restrict__ rp2,
                              const int* __restrict__ bsum, int nb, int n0, int n1, int n2,
                              int total) {
  __shared__ int sd[256];
  int r = blockIdx.y;
  int n = r == 0 ? n0 : (r == 1 ? n1 : n2);
  int* rp = r == 0 ? rp0 : (r == 1 ? rp1 : rp2);
  int t = threadIdx.x;
  int v = (t < nb) ? bsum[r * 256 + t] : 0;
  sd[t] = v;
  __syncthreads();
  for (int off = 1; off < 256; off <<= 1) {
    int u = (t >= off) ? sd[t - off] : 0;
    __syncthreads();
    sd[t] += u;
    __syncthreads();
  }
  int excl = sd[t] - v;
  __syncthreads();
  sd[t] = excl;
  __syncthreads();
  int i = blockIdx.x * 256 + t;
  if (i < n) rp[i] += sd[i >> 10];
  if (blockIdx.x == 0 && t == 0) rp[n] = total;
}

__global__ void scatter3_kernel(const int* __restrict__ s0, const int* __restrict__ d0,
                                const int* __restrict__ s1, const int* __restrict__ d1,
                                const int* __restrict__ s2, const int* __restrict__ d2,
                                const int* __restrict__ rp0, const int* __restrict__ rp1,
                                const int* __restrict__ rp2, int* __restrict__ cur, int maxN,
                                int* __restrict__ ss0, int* __restrict__ ss1,
                                int* __restrict__ ss2, int E) {
  int r = blockIdx.y;
  int i = blockIdx.x * 256 + threadIdx.x;
  if (i >= E) return;
  const int* src = r == 0 ? s0 : (r == 1 ? s1 : s2);
  const int* dst = r == 0 ? d0 : (r == 1 ? d1 : d2);
  const int* rp = r == 0 ? rp0 : (r == 1 ? rp1 : rp2);
  int* ss = r == 0 ? ss0 : (r == 1 ? ss1 : ss2);
  int d = dst[i];
  int pos = rp[d] + atomicAdd(&cur[(size_t)r * maxN + d], 1);
  ss[pos] = src[i];
}

// ---------- edge aggregation: one wave = one dst node, TWO edges per instruction ----------
// Lane l: half = l>>5 (edge parity within a pair), ll = l&31 owns elems 4ll..4ll+3 (uint2).
// Head = ll>>2 (4 lanes); head dot reduced with 2 quad DPP adds.
struct AggP {
  const unsigned *qb0, *qb1, *kv0, *kv1, *kv2;
  const int *rp0, *ss0, *rp1, *ss1, *rp2, *ss2;
  unsigned *Tb0, *Tb1;
  int N0, N1;
};

// load ss[p..p+7] and kv uint2 fragments for 8 edges (4 groups x 2 halves)
__device__ __forceinline__ void loadB(const char* __restrict__ kvl, const int* __restrict__ ss,
                                      int p, int end, int half, uint2 kb[4], uint2 vb[4]) {
  int lastp = end - 1;
  int idx = p + (threadIdx.x & 7);
  idx = idx > lastp ? lastp : idx;
  int sv = ss[idx];  // lanes 0..7 hold the 8 edge srcs
#pragma unroll
  for (int g = 0; g < 4; ++g) {
    int slo = __builtin_amdgcn_readlane(sv, 2 * g);
    int shi = __builtin_amdgcn_readlane(sv, 2 * g + 1);
    int s = half ? shi : slo;
    const char* r = kvl + ((size_t)(unsigned)s << 9);  // 512 B per node row
    kb[g] = *(const uint2*)r;
    vb[g] = *(const uint2*)(r + 256);
  }
}

__device__ __forceinline__ void computeB(int p, int end, int half, const uint2 kb[4],
                                         const uint2 vb[4], float qx0, float qy0, float qx1,
                                         float qy1, float& a0, float& a1, float& a2, float& a3,
                                         float& den) {
#pragma unroll
  for (int g = 0; g < 4; ++g) {
    float sc = qx0 * bflo(kb[g].x) + qy0 * bfhi(kb[g].x) + qx1 * bflo(kb[g].y) +
               qy1 * bfhi(kb[g].y);
    sc = DPPADD(sc, 0xB1);  // xor1 within quad
    sc = DPPADD(sc, 0x4E);  // xor2 within quad -> full 16-elem head sum
    float e = __expf(sc);
    e *= (p + 2 * g + half < end) ? 1.f : 0.f;  // tail mask (first edge always valid)
    den += e;
    a0 += e * bflo(vb[g].x);
    a1 += e * bfhi(vb[g].x);
    a2 += e * bflo(vb[g].y);
    a3 += e * bfhi(vb[g].y);
  }
}

__device__ __forceinline__ void accum_rel(const unsigned* __restrict__ kv,
                                          const int* __restrict__ rp, const int* __restrict__ ss,
                                          int node, int ll, int half, float qx0, float qy0,
                                          float qx1, float qy1, float& r0, float& r1, float& r2,
                                          float& r3) {
  int beg = __builtin_amdgcn_readfirstlane(rp[node]);
  int end = __builtin_amdgcn_readfirstlane(rp[node + 1]);
  if (end <= beg) return;
  const char* kvl = (const char*)kv + ll * 8;
  float a0 = 0.f, a1 = 0.f, a2 = 0.f, a3 = 0.f, den = 0.f;
  uint2 ka[4], va[4], kb[4], vb[4];
  int p = beg;
  loadB(kvl, ss, p, end, half, ka, va);
  for (;;) {
    if (p + 8 < end) loadB(kvl, ss, p + 8, end, half, kb, vb);
    computeB(p, end, half, ka, va, qx0, qy0, qx1, qy1, a0, a1, a2, a3, den);
    p += 8;
    if (p >= end) break;
    if (p + 8 < end) loadB(kvl, ss, p + 8, end, half, ka, va);
    computeB(p, end, half, kb, vb, qx0, qy0, qx1, qy1, a0, a1, a2, a3, den);
    p += 8;
    if (p >= end) break;
  }
  // combine the two 32-lane halves (each processed alternate edges)
  den += __shfl_xor(den, 32);
  a0 += __shfl_xor(a0, 32);
  a1 += __shfl_xor(a1, 32);
  a2 += __shfl_xor(a2, 32);
  a3 += __shfl_xor(a3, 32);
  float inv = 1.0f / den;
  r0 += a0 * inv;
  r1 += a1 * inv;
  r2 += a2 * inv;
  r3 += a3 * inv;
}

__global__ __launch_bounds__(256) void agg_all_kernel(AggP P) {
  int gw = (blockIdx.x * 256 + threadIdx.x) >> 6;
  int l = threadIdx.x & 63;
  int ll = l & 31, half = l >> 5;
  if (gw < P.N0) {
    uint2 q = *(const uint2*)(P.qb0 + (size_t)gw * 64 + 2 * ll);
    float qx0 = bflo(q.x), qy0 = bfhi(q.x), qx1 = bflo(q.y), qy1 = bfhi(q.y);
    float r0 = 0.f, r1 = 0.f, r2 = 0.f, r3 = 0.f;
    accum_rel(P.kv1, P.rp1, P.ss1, gw, ll, half, qx0, qy0, qx1, qy1, r0, r1, r2, r3);
    accum_rel(P.kv2, P.rp2, P.ss2, gw, ll, half, qx0, qy0, qx1, qy1, r0, r1, r2, r3);
    if (half == 0) {
      uint2 o;
      o.x = f2bf(r0 * 0.5f) | (f2bf(r1 * 0.5f) << 16);
      o.y = f2bf(r2 * 0.5f) | (f2bf(r3 * 0.5f) << 16);
      *(uint2*)(P.Tb0 + (size_t)gw * 64 + 2 * ll) = o;
    }
  } else if (gw < P.N0 + P.N1) {
    int n = gw - P.N0;
    uint2 q = *(const uint2*)(P.qb1 + (size_t)n * 64 + 2 * ll);
    float qx0 = bflo(q.x), qy0 = bfhi(q.x), qx1 = bflo(q.y), qy1 = bfhi(q.y);
    float r0 = 0.f, r1 = 0.f, r2 = 0.f, r3 = 0.f;
    accum_rel(P.kv0, P.rp0, P.ss0, n, ll, half, qx0, qy0, qx1, qy1, r0, r1, r2, r3);
    if (half == 0) {
      uint2 o;
      o.x = f2bf(r0) | (f2bf(r1) << 16);
      o.y = f2bf(r2) | (f2bf(r3) << 16);
      *(uint2*)(P.Tb1 + (size_t)n * 64 + 2 * ll) = o;
    }
  }
}

// ---------- host ----------
extern "C" void kernel_launch(void* const* d_in, const int* in_sizes, int n_in,
                              void* d_out, int out_size, void* d_ws, size_t ws_size,
                              hipStream_t stream) {
  const float* h0 = (const float*)d_in[0];
  const float* h1 = (const float*)d_in[1];
  const int* srcs[3] = {(const int*)d_in[2], (const int*)d_in[4], (const int*)d_in[6]};
  const int* dsts[3] = {(const int*)d_in[3], (const int*)d_in[5], (const int*)d_in[7]};
  const float* Wk = (const float*)d_in[8];
  const float* bk = (const float*)d_in[9];
  const float* Wq = (const float*)d_in[10];
  const float* bq = (const float*)d_in[11];
  const float* Wv = (const float*)d_in[12];
  const float* bv = (const float*)d_in[13];
  const float* Wa = (const float*)d_in[14];
  const float* ba = (const float*)d_in[15];
  const float* rel_att = (const float*)d_in[16];
  const float* rel_msg = (const float*)d_in[17];
  const float* rel_pri = (const float*)d_in[18];
  const float* skip = (const float*)d_in[19];

  int N0 = in_sizes[0] / 128;
  int N1 = in_sizes[1] / 128;
  int E = in_sizes[2];
  int nsrc[3] = {N0, N1, N0};
  int ndst[3] = {N1, N0, N0};
  int maxN = N0 > N1 ? N0 : N1;

  char* base = (char*)d_ws;
  size_t off = 0;
  auto alloc = [&](size_t bytes) -> void* {
    void* p = base + off;
    off += (bytes + 255) & ~(size_t)255;
    return p;
  };

  unsigned short* qb0 = (unsigned short*)alloc((size_t)N0 * 128 * 2);
  unsigned short* qb1 = (unsigned short*)alloc((size_t)N1 * 128 * 2);
  unsigned short* kvb[3];  // interleaved [N][kr(128) | vr(128)] bf16
  for (int r = 0; r < 3; ++r) kvb[r] = (unsigned short*)alloc((size_t)nsrc[r] * 256 * 2);
  unsigned short* Tb0 = (unsigned short*)alloc((size_t)N0 * 128 * 2);
  unsigned short* Tb1 = (unsigned short*)alloc((size_t)N1 * 128 * 2);
  unsigned short* Wkrb = (unsigned short*)alloc((size_t)3 * 16384 * 2);
  unsigned short* Wvrb = (unsigned short*)alloc((size_t)3 * 16384 * 2);
  unsigned short* Wqb = (unsigned short*)alloc((size_t)2 * 16384 * 2);
  unsigned short* Wab = (unsigned short*)alloc((size_t)2 * 16384 * 2);
  float* bkr = (float*)alloc(3 * 128 * 4);
  float* bvr = (float*)alloc(3 * 128 * 4);
  int* rp[3];
  int* ss[3];
  for (int r = 0; r < 3; ++r) {
    rp[r] = (int*)alloc((size_t)(ndst[r] + 1) * 4);
    ss[r] = (int*)alloc((size_t)(E + 8) * 4);
  }
  int* cnt6 = (int*)alloc((size_t)6 * maxN * 4);  // cnt (hist) + cur (scatter)
  int* bsum = (int*)alloc(3 * 256 * 4);
  (void)ws_size;

  // 1. weight prep
  compose_w_kernel<<<dim3(3, 128, 2), 128, 0, stream>>>(Wk, bk, Wv, bv, rel_att, rel_msg,
                                                        rel_pri, Wkrb, bkr, Wvrb, bvr);
  cvt2_kernel<<<dim3(16, 2), 256, 0, stream>>>(Wq, Wqb, Wa, Wab, 4096);

  // 2. fused projection GEMMs -> bf16 q + interleaved kv tables
  ProjFP pf;
  pf.A[0] = h0; pf.A[1] = h1;
  pf.M[0] = N0; pf.M[1] = N1;
  pf.nj[0] = 5; pf.nj[1] = 3;
  // type0 jobs: q, kr(rel0), kr(rel2), vr(rel0), vr(rel2)
  pf.W[0] = Wqb;            pf.b[0] = bq;        pf.out[0] = qb0;          pf.ostr[0] = 128;
  pf.W[1] = Wkrb;           pf.b[1] = bkr;       pf.out[1] = kvb[0];       pf.ostr[1] = 256;
  pf.W[2] = Wkrb + 32768;   pf.b[2] = bkr + 256; pf.out[2] = kvb[2];       pf.ostr[2] = 256;
  pf.W[3] = Wvrb;           pf.b[3] = bvr;       pf.out[3] = kvb[0] + 128; pf.ostr[3] = 256;
  pf.W[4] = Wvrb + 32768;   pf.b[4] = bvr + 256; pf.out[4] = kvb[2] + 128; pf.ostr[4] = 256;
  // type1 jobs: q, kr(rel1), vr(rel1)
  pf.W[5] = Wqb + 16384;    pf.b[5] = bq + 128;  pf.out[5] = qb1;          pf.ostr[5] = 128;
  pf.W[6] = Wkrb + 16384;   pf.b[6] = bkr + 128; pf.out[6] = kvb[1];       pf.ostr[6] = 256;
  pf.W[7] = Wvrb + 16384;   pf.b[7] = bvr + 128; pf.out[7] = kvb[1] + 128; pf.ostr[7] = 256;
  pf.W[8] = Wqb; pf.b[8] = bq; pf.out[8] = qb0; pf.ostr[8] = 128;  // unused
  pf.W[9] = Wqb; pf.b[9] = bq; pf.out[9] = qb0; pf.ostr[9] = 128;  // unused
  proj_gemm_fused<<<dim3((maxN + 127) / 128, 2), 256, 0, stream>>>(pf);

  // 3. CSR per relation (batched, gridDim.y = 3)
  hipMemsetAsync(cnt6, 0, (size_t)6 * maxN * 4, stream);
  hist3_kernel<<<dim3((E + 255) / 256, 3), 256, 0, stream>>>(dsts[0], dsts[1], dsts[2], cnt6,
                                                             maxN, E);
  int nb = (maxN + 1023) / 1024;
  scan1_kernel<<<dim3(nb, 3), 256, 0, stream>>>(cnt6, rp[0], rp[1], rp[2], bsum, maxN,
                                                ndst[0], ndst[1], ndst[2]);
  scan23_kernel<<<dim3((maxN + 255) / 256, 3), 256, 0, stream>>>(
      rp[0], rp[1], rp[2], bsum, nb, ndst[0], ndst[1], ndst[2], E);
  scatter3_kernel<<<dim3((E + 255) / 256, 3), 256, 0, stream>>>(
      srcs[0], dsts[0], srcs[1], dsts[1], srcs[2], dsts[2], rp[0], rp[1], rp[2],
      cnt6 + (size_t)3 * maxN, maxN, ss[0], ss[1], ss[2], E);

  // 4. edge aggregation -> bf16 T (one kernel, both types)
  AggP ap;
  ap.qb0 = (const unsigned*)qb0; ap.qb1 = (const unsigned*)qb1;
  ap.kv0 = (const unsigned*)kvb[0]; ap.kv1 = (const unsigned*)kvb[1];
  ap.kv2 = (const unsigned*)kvb[2];
  ap.rp0 = rp[0]; ap.ss0 = ss[0];
  ap.rp1 = rp[1]; ap.ss1 = ss[1];
  ap.rp2 = rp[2]; ap.ss2 = ss[2];
  ap.Tb0 = (unsigned*)Tb0; ap.Tb1 = (unsigned*)Tb1;
  ap.N0 = N0; ap.N1 = N1;
  int totw = N0 + N1;
  agg_all_kernel<<<(totw + 3) / 4, 256, 0, stream>>>(ap);

  // 5. final GEMM + skip blend -> fp32 d_out
  final_gemm_mfma<<<dim3((maxN + 127) / 128, 2), 256, 0, stream>>>(
      (float*)d_out, Tb0, Tb1, Wab, ba, h0, h1, skip, N0, N1);
}